// Round 2
// baseline (77.679 us; speedup 1.0000x reference)
//
#include <hip/hip_runtime.h>

// Problem constants (fixed by the reference setup_inputs()).
#define F_DIM   1024   // in_features
#define O_DIM   1024   // out_features
#define W_DIM   7      // DEGREE - START_DEGREE + 1
#define BLOCK   256
#define RB      4      // rows per block: 1 row per wave, 4 waves

// v3: two-kernel, zero-LDS, zero-barrier design.
//   Post-mortem of v2 (~29 us kernel vs ~6-8 us model): the per-block
//   serialized prologue (28 KiB LDS staging + __syncthreads BEFORE any
//   compute, whose s_waitcnt vmcnt(0) lgkmcnt(0) also drains the x loads)
//   put ~1 us of dead latency on every block's critical path and capped
//   occupancy. v3 removes the mechanism entirely:
//   1. transpose_coeffs (28 blocks, ~2 us) writes ct[w][o] into d_ws once.
//   2. hermite_fused: each wave owns one row end-to-end. No LDS, no
//      barriers, no inter-wave deps. Epilogue reads ct + w*1024 + 4k:
//      lane stride 16 B -> 1 KiB/instr coalesced, L1-resident (28 KiB).
__global__ void transpose_coeffs(const float* __restrict__ coeffs,
                                 float* __restrict__ ct) {
    const int t = blockIdx.x * blockDim.x + threadIdx.x;   // 0..7167
    if (t < O_DIM * W_DIM) {
        const int o = t / W_DIM;       // coalesced read of coeffs[o][w]
        const int w = t - o * W_DIM;
        ct[w * O_DIM + o] = coeffs[t]; // scattered write, 28 KiB total
    }
}

__global__ __launch_bounds__(BLOCK, 4) void hermite_fused(
    const float* __restrict__ x,       // (B, F)
    const float* __restrict__ ct,      // (W, O) transposed coeffs in d_ws
    const float* __restrict__ sigma,   // (1,)
    float* __restrict__ out)           // (B, O)
{
    const int tid  = threadIdx.x;
    const int lane = tid & 63;
    const int wave = tid >> 6;
    const int row  = blockIdx.x * RB + wave;   // this wave's row

    // ---- issue this wave's x loads immediately ----
    const float4* xrow = (const float4*)(x + (size_t)row * F_DIM);
    float4 v[4];
    v[0] = xrow[lane];
    v[1] = xrow[lane + 64];
    v[2] = xrow[lane + 128];
    v[3] = xrow[lane + 192];

    const float s     = fminf(fmaxf(sigma[0], 0.1f), 5.0f);
    const float inv_s = 1.0f / s;

    // ---- phase 1: Hermite basis for this wave's row ----
    float acc[W_DIM];
#pragma unroll
    for (int w = 0; w < W_DIM; ++w) acc[w] = 0.0f;

#pragma unroll
    for (int q = 0; q < 4; ++q) {
        const float el[4] = {v[q].x, v[q].y, v[q].z, v[q].w};
#pragma unroll
        for (int e = 0; e < 4; ++e) {
            const float xs = el[e] * inv_s;
            const float g  = __expf(-fminf(xs * xs, 50.0f));
            // H0=1, H1=2x, Hn = 2x*H_{n-1} - 2(n-1)*H_{n-2}; clip Hn
            // (n>=2) to [-100,100] before it feeds the next step (ref).
            float hm2 = 1.0f;
            float hm1 = 2.0f * xs;
            acc[0] += g;
            acc[1] += hm1 * g;
#pragma unroll
            for (int n = 2; n <= 6; ++n) {
                float hn = 2.0f * xs * hm1 - 2.0f * (float)(n - 1) * hm2;
                hn = fminf(fmaxf(hn, -100.0f), 100.0f);   // v_med3
                acc[n] += hn * g;
                hm2 = hm1;
                hm1 = hn;
            }
        }
    }

    // xor-butterfly: every lane ends with the full row sum
    float basis[W_DIM];
#pragma unroll
    for (int w = 0; w < W_DIM; ++w) {
        float a = acc[w];
#pragma unroll
        for (int m = 32; m > 0; m >>= 1)
            a += __shfl_xor(a, m, 64);
        basis[w] = a;
    }

    // ---- phase 2: epilogue from transposed coeffs (global, L1-hot) ----
    float* orow = out + (size_t)row * O_DIM;
#pragma unroll
    for (int q = 0; q < 4; ++q) {
        const int k = q * 64 + lane;           // float4 index within row
        float4 a;
        {
            const float4 c = *(const float4*)(ct + 4 * k);
            a.x = basis[0] * c.x; a.y = basis[0] * c.y;
            a.z = basis[0] * c.z; a.w = basis[0] * c.w;
        }
#pragma unroll
        for (int w = 1; w < W_DIM; ++w) {
            const float4 c  = *(const float4*)(ct + w * O_DIM + 4 * k);
            const float bw = basis[w];
            a.x = fmaf(bw, c.x, a.x);
            a.y = fmaf(bw, c.y, a.y);
            a.z = fmaf(bw, c.z, a.z);
            a.w = fmaf(bw, c.w, a.w);
        }
        ((float4*)orow)[k] = a;
    }
}

extern "C" void kernel_launch(void* const* d_in, const int* in_sizes, int n_in,
                              void* d_out, int out_size, void* d_ws, size_t ws_size,
                              hipStream_t stream) {
    const float* x      = (const float*)d_in[0];  // (B, F) fp32
    const float* coeffs = (const float*)d_in[1];  // (O, W) fp32
    const float* sigma  = (const float*)d_in[2];  // (1,)   fp32
    float* out          = (float*)d_out;          // (B, O) fp32
    float* ct           = (float*)d_ws;           // (W, O) fp32, 28 KiB

    const int B = in_sizes[0] / F_DIM;
    transpose_coeffs<<<dim3((O_DIM * W_DIM + BLOCK - 1) / BLOCK), dim3(BLOCK),
                       0, stream>>>(coeffs, ct);
    hermite_fused<<<dim3(B / RB), dim3(BLOCK), 0, stream>>>(x, ct, sigma, out);
}

// Round 3
// 75.112 us; speedup vs baseline: 1.0342x; 1.0342x over previous
//
#include <hip/hip_runtime.h>

// Problem constants (fixed by the reference setup_inputs()).
#define F_DIM   1024   // in_features
#define O_DIM   1024   // out_features
#define W_DIM   7      // DEGREE - START_DEGREE + 1
#define BLOCK   256
#define RB      4      // rows per block: 1 row per wave, 4 waves

// v4: single launch (v3's 2nd dispatch cost ~4 us), v2's LDS-transposed
// epilogue, but the barrier moved to where it's free:
//   issue x loads -> issue coeff loads -> Hermite compute (waits x only,
//   coeff loads stay in flight) -> transposed ds_write_b128 staging ->
//   butterfly -> __syncthreads -> epilogue from LDS.
// v2 had the barrier BEFORE compute, putting staging drain (vmcnt(0) +
// lgkmcnt(0)) on every wave's critical path. Here ~1500 cyc of Hermite
// hides the staging latency and the barrier arrives pre-drained.
// Window model (fit across v1-v3): dur_us = 44.5 poison fill + ~24 reset
// dispatch train + kernel. Kernel is ~5-8 us vs 5.3 us traffic floor
// (33.6 MB @ 6.3 TB/s); if this lands >=73 us the kernel is at floor.
__global__ __launch_bounds__(BLOCK, 4) void hermite_fused(
    const float* __restrict__ x,       // (B, F)
    const float* __restrict__ coeffs,  // (O, W)
    const float* __restrict__ sigma,   // (1,)
    float* __restrict__ out)           // (B, O)
{
    const int tid  = threadIdx.x;
    const int lane = tid & 63;
    const int wave = tid >> 6;
    const int row  = blockIdx.x * RB + wave;   // this wave's row

    __shared__ float ct[W_DIM][O_DIM];         // transposed coeffs, 28 KiB

    // ---- issue this wave's x loads first ----
    const float4* xrow = (const float4*)(x + (size_t)row * F_DIM);
    float4 v[4];
    v[0] = xrow[lane];
    v[1] = xrow[lane + 64];
    v[2] = xrow[lane + 128];
    v[3] = xrow[lane + 192];

    // ---- issue coeff loads (thread t owns outputs o = 4t..4t+3) ----
    // 7 contiguous float4s = floats [28t, 28t+28). These stay in flight
    // through phase 1 (no use until the ds_writes below).
    float4 c4[7];
    {
        const float4* cg = (const float4*)coeffs + 7 * tid;
#pragma unroll
        for (int j = 0; j < 7; ++j) c4[j] = cg[j];
    }

    const float s     = fminf(fmaxf(sigma[0], 0.1f), 5.0f);
    const float inv_s = 1.0f / s;

    // ---- phase 1: Hermite basis (waits only on x loads) ----
    float acc[W_DIM];
#pragma unroll
    for (int w = 0; w < W_DIM; ++w) acc[w] = 0.0f;

#pragma unroll
    for (int q = 0; q < 4; ++q) {
        const float el[4] = {v[q].x, v[q].y, v[q].z, v[q].w};
#pragma unroll
        for (int e = 0; e < 4; ++e) {
            const float xs = el[e] * inv_s;
            const float g  = __expf(-fminf(xs * xs, 50.0f));
            // H0=1, H1=2x, Hn = 2x*H_{n-1} - 2(n-1)*H_{n-2}; clip Hn
            // (n>=2) to [-100,100] before it feeds the next step (ref).
            float hm2 = 1.0f;
            float hm1 = 2.0f * xs;
            acc[0] += g;
            acc[1] += hm1 * g;
#pragma unroll
            for (int n = 2; n <= 6; ++n) {
                float hn = 2.0f * xs * hm1 - 2.0f * (float)(n - 1) * hm2;
                hn = fminf(fmaxf(hn, -100.0f), 100.0f);   // v_med3
                acc[n] += hn * g;
                hm2 = hm1;
                hm1 = hn;
            }
        }
    }

    // ---- transposed staging: 7 ds_write_b128 per thread ----
    // tmp float [o-minor]: c4[j] holds floats 4j..4j+3 of the 28-float
    // run, i.e. (o = 4t + (4j+e)/7 ... ) -- easier: flatten then regroup.
    {
        float tf[28];
#pragma unroll
        for (int j = 0; j < 7; ++j) {
            tf[4 * j + 0] = c4[j].x; tf[4 * j + 1] = c4[j].y;
            tf[4 * j + 2] = c4[j].z; tf[4 * j + 3] = c4[j].w;
        }
        // tf[i] = coeffs[4t + i/7][i%7]; for fixed w the 4 outputs
        // 4t..4t+3 are tf[w], tf[7+w], tf[14+w], tf[21+w] -> one b128.
        const int o0 = 4 * tid;
#pragma unroll
        for (int w = 0; w < W_DIM; ++w) {
            float4 r;
            r.x = tf[w]; r.y = tf[7 + w]; r.z = tf[14 + w]; r.w = tf[21 + w];
            *(float4*)&ct[w][o0] = r;
        }
    }

    // ---- butterfly (wave-local; overlaps ds_write drain) ----
    float basis[W_DIM];
#pragma unroll
    for (int w = 0; w < W_DIM; ++w) {
        float a = acc[w];
#pragma unroll
        for (int m = 32; m > 0; m >>= 1)
            a += __shfl_xor(a, m, 64);
        basis[w] = a;
    }

    __syncthreads();   // staging visible; all latency already hidden

    // ---- phase 2: epilogue from LDS (conflict-free ds_read_b128) ----
    float* orow = out + (size_t)row * O_DIM;
#pragma unroll
    for (int q = 0; q < 4; ++q) {
        const int k = q * 64 + lane;           // float4 index within row
        float4 a;
        {
            const float4 c = *(const float4*)&ct[0][4 * k];
            a.x = basis[0] * c.x; a.y = basis[0] * c.y;
            a.z = basis[0] * c.z; a.w = basis[0] * c.w;
        }
#pragma unroll
        for (int w = 1; w < W_DIM; ++w) {
            const float4 c  = *(const float4*)&ct[w][4 * k];
            const float bw = basis[w];
            a.x = fmaf(bw, c.x, a.x);
            a.y = fmaf(bw, c.y, a.y);
            a.z = fmaf(bw, c.z, a.z);
            a.w = fmaf(bw, c.w, a.w);
        }
        ((float4*)orow)[k] = a;
    }
}

extern "C" void kernel_launch(void* const* d_in, const int* in_sizes, int n_in,
                              void* d_out, int out_size, void* d_ws, size_t ws_size,
                              hipStream_t stream) {
    const float* x      = (const float*)d_in[0];  // (B, F) fp32
    const float* coeffs = (const float*)d_in[1];  // (O, W) fp32
    const float* sigma  = (const float*)d_in[2];  // (1,)   fp32
    float* out          = (float*)d_out;          // (B, O) fp32

    const int B = in_sizes[0] / F_DIM;
    hermite_fused<<<dim3(B / RB), dim3(BLOCK), 0, stream>>>(x, coeffs, sigma, out);
}